// Round 6
// baseline (406.309 us; speedup 1.0000x reference)
//
#include <hip/hip_runtime.h>
#include <cstddef>

// Problem constants (static per reference)
#define B_ 2
#define Q_ 300
#define T_ 25
#define C_ 256
#define NH_ 8
#define NL_ 4
#define NP_ 4
#define HD_ 32
#define DFF_ 1024
#define LQ_ (Q_ * T_)           // 7500
#define NTOK_ (B_ * LQ_)        // 15000
#define S_ 21760                // sum of level sizes
#define BS_ (B_ * S_)           // 43520

typedef __bf16 bf16x8 __attribute__((ext_vector_type(8)));
typedef float floatx4 __attribute__((ext_vector_type(4)));
typedef unsigned short ushort_t;

// round-half-up bf16 pack: lo16 = bf16(x), hi16 = bf16(y). Folds to v_perm.
__device__ __forceinline__ unsigned pack_bf16(float x, float y) {
    unsigned ux = __float_as_uint(x) + 0x8000u;
    unsigned uy = __float_as_uint(y) + 0x8000u;
    return (ux >> 16) | (uy & 0xFFFF0000u);
}
__device__ __forceinline__ ushort_t f2bf_s(float x) {
    return (ushort_t)((__float_as_uint(x) + 0x8000u) >> 16);
}
__device__ __forceinline__ float bf2f(ushort_t u) {
    return __uint_as_float((unsigned)u << 16);
}

// bf16 weight arena element offsets (all static shapes)
#define WOFF_IP   0         // in_proj   768x256
#define WOFF_OUT  196608    // out_proj  256x256
#define WOFF_VP   262144    // value_proj 256x256
#define WOFF_SO   327680    // samp_off  256x256  (contiguous with aw -> 384x256)
#define WOFF_AW   393216    // aw        128x256
#define WOFF_OP   425984    // op        256x256
#define WOFF_F1   491520    // ffn1      1024x256
#define WOFF_F2   753664    // ffn2      256x1024
#define WTOTAL    1015808

// ---------------- one-shot fp32 -> bf16 weight conversion (8 elems/thread) ----------------
__global__ __launch_bounds__(256) void convw_kernel(
    const float* __restrict__ ipw, const float* __restrict__ outw,
    const float* __restrict__ vpw, const float* __restrict__ sampw,
    const float* __restrict__ aww, const float* __restrict__ opw,
    const float* __restrict__ f1w, const float* __restrict__ f2w,
    ushort_t* __restrict__ dst)
{
    long long g = ((long long)blockIdx.x * 256 + threadIdx.x) * 8;
    if (g >= WTOTAL) return;
    const float* src; long long off;
    if      (g < WOFF_OUT) { src = ipw;   off = WOFF_IP; }
    else if (g < WOFF_VP)  { src = outw;  off = WOFF_OUT; }
    else if (g < WOFF_SO)  { src = vpw;   off = WOFF_VP; }
    else if (g < WOFF_AW)  { src = sampw; off = WOFF_SO; }
    else if (g < WOFF_OP)  { src = aww;   off = WOFF_AW; }
    else if (g < WOFF_F1)  { src = opw;   off = WOFF_OP; }
    else if (g < WOFF_F2)  { src = f1w;   off = WOFF_F1; }
    else                   { src = f2w;   off = WOFF_F2; }
    const float4* s4 = (const float4*)(src + (g - off));
    float4 a = s4[0], b = s4[1];
    uint4 o;
    o.x = pack_bf16(a.x, a.y); o.y = pack_bf16(a.z, a.w);
    o.z = pack_bf16(b.x, b.y); o.w = pack_bf16(b.z, b.w);
    *(uint4*)(dst + g) = o;
}

#define GBN 128
#define GBK 64     // K-step: 2 MFMA-subtiles per barrier pair
#define LDA_S 72   // LDS row stride in bf16 (64 + 8 pad; 144B rows, 16B-aligned frags)

// ---------------- bf16-MFMA GEMM; W pre-converted bf16; 1-deep prefetch; split-K ----------
// AMODE: 0 = A fp32; 1 = A fp32 + A2 fp32 added ONLY for blocks with n0 < N1
//        (fused QKV); 2 = A bf16.
// OUTMODE: 0 = fp32 C (split-K capable; 64B/quarter stores = full lines already);
//          1 = bf16 C via LDS-restaged coalesced epilogue (full uint4 lines);
//          2 = bf16 C transposed value layout [B][NH][S][HD], same LDS restage.
// Grid-x padded to %8==0 by host (pad blocks exit on m0>=M): same-x blocks share
// an XCD -> A panel re-reads across y/z are L2 hits.
template<int AMODE, int OUTMODE, int GBMT>
__global__ __launch_bounds__(256) void gemm_w(
    const void* __restrict__ Av, const float* __restrict__ A2,
    const ushort_t* __restrict__ W,
    const float* __restrict__ bias, const float* __restrict__ bias2, int N1,
    void* __restrict__ Cv, long long partStride,
    int M, int N, int K, int kChunk, int ldc, int relu)
{
    constexpr int LA = GBMT / 16;   // A 4-elem chunks per thread
    constexpr int LB = 8;           // W 4-elem chunks per thread
    constexpr int WM = GBMT / 2;
    constexpr int NI = WM / 16;

    // union arena: staging tiles during K-loop; bf16 epilogue restage after
    __shared__ unsigned short SH[GBMT * LDA_S + GBN * LDA_S];
    unsigned short* Asl = SH;
    unsigned short* Bsl = SH + GBMT * LDA_S;

    const int m0 = blockIdx.x * GBMT;
    if (m0 >= M) return;                   // XCD-alignment pad block
    const int n0 = blockIdx.y * GBN;
    const int z  = blockIdx.z;
    const int kbeg = z * kChunk;
    const int kend = min(K, kbeg + kChunk);

    const int t  = threadIdx.x;
    const int wid  = t >> 6;
    const int lane = t & 63;
    const int wm = (wid >> 1) * WM;
    const int wn = (wid & 1) * 64;
    const int fm = lane & 15;
    const int fq = (lane >> 4) * 8;

    const bool addA2 = (AMODE == 1) && (n0 < N1);

    floatx4 acc[NI][4];
    #pragma unroll
    for (int i = 0; i < NI; ++i)
        #pragma unroll
        for (int j = 0; j < 4; ++j)
            acc[i][j] = (floatx4){0.f, 0.f, 0.f, 0.f};

    float4 pa[LA];
    uint2  pab[LA];
    uint2  pwb[LB];
    const float* Af = (const float*)Av;
    const ushort_t* Ab = (const ushort_t*)Av;

    auto load_tiles = [&](int k0) {
        #pragma unroll
        for (int i = 0; i < LA; ++i) {
            int idx = t + 256 * i;
            int row = idx >> 4;
            int c4  = (idx & 15) * 4;
            int gm = m0 + row;
            if constexpr (AMODE == 2) {
                uint2 v = {0u, 0u};
                if (gm < M) v = *(const uint2*)(Ab + (size_t)gm * K + k0 + c4);
                pab[i] = v;
            } else {
                float4 v = make_float4(0.f, 0.f, 0.f, 0.f);
                if (gm < M) {
                    v = *(const float4*)(Af + (size_t)gm * K + k0 + c4);
                    if constexpr (AMODE == 1) {
                        if (addA2) {
                            float4 v2 = *(const float4*)(A2 + (size_t)gm * K + k0 + c4);
                            v.x += v2.x; v.y += v2.y; v.z += v2.z; v.w += v2.w;
                        }
                    }
                }
                pa[i] = v;
            }
        }
        #pragma unroll
        for (int i = 0; i < LB; ++i) {
            int idx = t + 256 * i;
            int row = idx >> 4;
            int c4  = (idx & 15) * 4;
            pwb[i] = *(const uint2*)(W + (size_t)(n0 + row) * K + k0 + c4);
        }
    };

    load_tiles(kbeg);
    for (int k0 = kbeg; k0 < kend; k0 += GBK) {
        #pragma unroll
        for (int i = 0; i < LA; ++i) {
            int idx = t + 256 * i;
            int row = idx >> 4;
            int c4  = (idx & 15) * 4;
            if constexpr (AMODE == 2) {
                *(uint2*)&Asl[row * LDA_S + c4] = pab[i];
            } else {
                uint2 p;
                p.x = pack_bf16(pa[i].x, pa[i].y);
                p.y = pack_bf16(pa[i].z, pa[i].w);
                *(uint2*)&Asl[row * LDA_S + c4] = p;
            }
        }
        #pragma unroll
        for (int i = 0; i < LB; ++i) {
            int idx = t + 256 * i;
            int row = idx >> 4;
            int c4  = (idx & 15) * 4;
            *(uint2*)&Bsl[row * LDA_S + c4] = pwb[i];
        }
        __syncthreads();
        // issue next-tile loads here: they stay in flight across ds_read+MFMA
        if (k0 + GBK < kend) load_tiles(k0 + GBK);

        #pragma unroll
        for (int kk = 0; kk < 2; ++kk) {
            bf16x8 af[NI], bfr[4];
            #pragma unroll
            for (int i = 0; i < NI; ++i)
                af[i] = *(const bf16x8*)&Asl[(wm + i * 16 + fm) * LDA_S + kk * 32 + fq];
            #pragma unroll
            for (int j = 0; j < 4; ++j)
                bfr[j] = *(const bf16x8*)&Bsl[(wn + j * 16 + fm) * LDA_S + kk * 32 + fq];

            #pragma unroll
            for (int i = 0; i < NI; ++i)
                #pragma unroll
                for (int j = 0; j < 4; ++j)
                    acc[i][j] = __builtin_amdgcn_mfma_f32_16x16x32_bf16(af[i], bfr[j], acc[i][j], 0, 0, 0);
        }
        __syncthreads();
    }

    // epilogue: C/D layout col=lane&15, row=(lane>>4)*4+reg
    float* Cf = (float*)Cv + (long long)z * partStride;
    ushort_t* Cb = (ushort_t*)Cv;
    const int cr = (lane >> 4) * 4;
    const int cc = lane & 15;

    if constexpr (OUTMODE == 0) {
        // fp32: 16 lanes x 4B = 64B per row-quarter -> already full-line stores
        #pragma unroll
        for (int j = 0; j < 4; ++j) {
            int gn = n0 + wn + j * 16 + cc;
            float bia = 0.f;
            if (z == 0) bia = (bias2 && gn >= N1) ? bias2[gn - N1] : bias[gn];
            #pragma unroll
            for (int i = 0; i < NI; ++i)
                #pragma unroll
                for (int r = 0; r < 4; ++r) {
                    int gm = m0 + wm + i * 16 + cr + r;
                    if (gm < M) {
                        float v = acc[i][j][r] + bia;
                        if (relu) v = fmaxf(v, 0.f);
                        Cf[(size_t)gm * ldc + gn] = v;
                    }
                }
        }
    } else {
        // bf16: restage wave's WM x 64 sub-tile in LDS, then full-line uint4 stores.
        // Safe to reuse SH: final K-loop barrier ordered all ds_reads before here.
        unsigned short* epi = SH + wid * (WM * 64);
        #pragma unroll
        for (int j = 0; j < 4; ++j) {
            int gn = n0 + wn + j * 16 + cc;
            float bia = (bias2 && gn >= N1) ? bias2[gn - N1] : bias[gn];
            #pragma unroll
            for (int i = 0; i < NI; ++i)
                #pragma unroll
                for (int r = 0; r < 4; ++r) {
                    float v = acc[i][j][r] + bia;
                    if (relu) v = fmaxf(v, 0.f);
                    epi[(i * 16 + cr + r) * 64 + j * 16 + cc] = f2bf_s(v);
                }
        }
        // read back linear (lane l reads byte 16*l of the wave region: conflict-free)
        #pragma unroll
        for (int pass = 0; pass < WM / 8; ++pass) {
            int lr = pass * 8 + (lane >> 3);
            int gm = m0 + wm + lr;
            uint4 vv = *(const uint4*)&epi[lr * 64 + (lane & 7) * 8];
            if (gm < M) {
                if constexpr (OUTMODE == 1) {
                    *(uint4*)&Cb[(size_t)gm * ldc + n0 + wn + (lane & 7) * 8] = vv;
                } else {
                    int bb = gm >= S_;
                    int s  = gm - bb * S_;
                    int gh = n0 + wn + (lane & 7) * 8;   // 8 elems stay in one 32-col head
                    *(uint4*)&Cb[(((size_t)(bb * 8 + (gh >> 5))) * S_ + s) * 32 + (gh & 31)] = vv;
                }
            }
        }
    }
}

// ---------------- self-attention over T=25, one wave per (seq, head); bf16 in/out ----------------
__global__ __launch_bounds__(64) void attn_kernel(
    const ushort_t* __restrict__ qkv,   // [NTOK, 768] bf16: q|k|v per token
    ushort_t* __restrict__ o)           // [NTOK, 256] bf16
{
    int sh = blockIdx.x;
    int s = sh >> 3, h = sh & 7;
    __shared__ float qs[T_][HD_], ks[T_][HD_], vs[T_][HD_];
    int t = threadIdx.x;

    for (int idx = t; idx < T_ * HD_; idx += 64) {
        int i = idx >> 5, d = idx & 31;
        size_t base = ((size_t)(s * T_ + i)) * 768 + h * HD_ + d;
        qs[i][d] = bf2f(qkv[base]);
        ks[i][d] = bf2f(qkv[base + 256]);
        vs[i][d] = bf2f(qkv[base + 512]);
    }
    __syncthreads();

    if (t < T_) {
        float sc[T_];
        float mx = -1e30f;
        #pragma unroll
        for (int j = 0; j < T_; ++j) {
            float dot = 0.f;
            #pragma unroll
            for (int d = 0; d < HD_; ++d) dot += qs[t][d] * ks[j][d];
            sc[j] = dot * 0.17677669529663687f;
            mx = fmaxf(mx, sc[j]);
        }
        float sum = 0.f;
        #pragma unroll
        for (int j = 0; j < T_; ++j) { sc[j] = __expf(sc[j] - mx); sum += sc[j]; }
        float inv = 1.f / sum;
        float out[HD_];
        #pragma unroll
        for (int d = 0; d < HD_; ++d) out[d] = 0.f;
        for (int j = 0; j < T_; ++j) {
            float p = sc[j] * inv;
            #pragma unroll
            for (int d = 0; d < HD_; ++d) out[d] += p * vs[j][d];
        }
        size_t ob = ((size_t)(s * T_ + t)) * C_ + h * HD_;
        #pragma unroll
        for (int d = 0; d < HD_; ++d) o[ob + d] = f2bf_s(out[d]);
    }
}

// ---------------- wave-per-token residual + LayerNorm (float4, no LDS) ----------------
// NOTE: r/out/qout may alias the same workspace region (split-K partial reuse)
// -> no __restrict__ on them.
__global__ __launch_bounds__(256) void ln4_kernel(
    const float* x, const float* r,
    int nparts, long long rstride,
    const float* __restrict__ g, const float* __restrict__ b,
    float* out, const float* __restrict__ pos,
    float* qout)
{
    const int wave = threadIdx.x >> 6;
    const int lane = threadIdx.x & 63;
    const int tok = blockIdx.x * 4 + wave;
    const size_t base = (size_t)tok * C_ + lane * 4;

    float4 v = *(const float4*)(x + base);
    for (int p = 0; p < nparts; ++p) {
        float4 rv = *(const float4*)(r + base + (long long)p * rstride);
        v.x += rv.x; v.y += rv.y; v.z += rv.z; v.w += rv.w;
    }
    float s  = v.x + v.y + v.z + v.w;
    float ss = v.x * v.x + v.y * v.y + v.z * v.z + v.w * v.w;
    #pragma unroll
    for (int m = 32; m; m >>= 1) {
        s  += __shfl_xor(s, m);
        ss += __shfl_xor(ss, m);
    }
    float mean = s * (1.f / 256.f);
    float var  = ss * (1.f / 256.f) - mean * mean;
    float rstd = rsqrtf(var + 1e-5f);

    float4 gv = *(const float4*)(g + lane * 4);
    float4 bv = *(const float4*)(b + lane * 4);
    float4 y;
    y.x = (v.x - mean) * rstd * gv.x + bv.x;
    y.y = (v.y - mean) * rstd * gv.y + bv.y;
    y.z = (v.z - mean) * rstd * gv.z + bv.z;
    y.w = (v.w - mean) * rstd * gv.w + bv.w;
    *(float4*)(out + base) = y;
    if (qout) {
        float4 pv = *(const float4*)(pos + base);
        float4 q;
        q.x = y.x + pv.x; q.y = y.y + pv.y; q.z = y.z + pv.z; q.w = y.w + pv.w;
        *(float4*)(qout + base) = q;
    }
}

// ---------------- deformable sampling, XCD-plane-local + LDS-staged params ----------------
#define DCHUNK_ 118   // ceil(7500 / 64)
__global__ __launch_bounds__(256) void deform_kernel(
    const ushort_t* __restrict__ value,   // [B][NH][S][HD] bf16 (transposed)
    const float* __restrict__ d12,        // [NTOK, 384] = offsets | aw logits
    const float* __restrict__ refpts,     // [B, LQ, NL, 2]
    ushort_t* __restrict__ out)           // [NTOK, 256] bf16, laid out (tok, h, d)
{
    const int bi    = blockIdx.x;          // [0, 8*2*DCHUNK_)
    const int xcd   = bi & 7;
    const int yy    = bi >> 3;
    const int combo = xcd + 8 * (yy & 1);  // == b*8 + h, in [0,16)
    const int chunk = yy >> 1;             // [0, DCHUNK_)
    const int h     = combo & 7;
    const int b     = combo >> 3;

    // per-token row: [0..31] offsets, [32..47] softmax weights, [48..55] refpts
    __shared__ float tls[64][60];

    const int tid = threadIdx.x;
    const int t0  = chunk * 64;

    // stage offsets: 64 tokens x 8 float4 (512 float4, 2/thread)
    #pragma unroll
    for (int i = 0; i < 2; ++i) {
        int idx  = tid + 256 * i;
        int trow = idx >> 3;
        int c4   = (idx & 7) * 4;
        int tl   = min(t0 + trow, LQ_ - 1);
        float4 v;
        v.x = __builtin_nontemporal_load(d12 + (size_t)(b * LQ_ + tl) * 384 + h * 32 + c4 + 0);
        v.y = __builtin_nontemporal_load(d12 + (size_t)(b * LQ_ + tl) * 384 + h * 32 + c4 + 1);
        v.z = __builtin_nontemporal_load(d12 + (size_t)(b * LQ_ + tl) * 384 + h * 32 + c4 + 2);
        v.w = __builtin_nontemporal_load(d12 + (size_t)(b * LQ_ + tl) * 384 + h * 32 + c4 + 3);
        *(float4*)&tls[trow][c4] = v;
    }
    // stage aw logits: 64 tokens x 4 float4
    {
        int trow = tid >> 2;
        int c4   = (tid & 3) * 4;
        int tl   = min(t0 + trow, LQ_ - 1);
        float4 v;
        v.x = __builtin_nontemporal_load(d12 + (size_t)(b * LQ_ + tl) * 384 + 256 + h * 16 + c4 + 0);
        v.y = __builtin_nontemporal_load(d12 + (size_t)(b * LQ_ + tl) * 384 + 256 + h * 16 + c4 + 1);
        v.z = __builtin_nontemporal_load(d12 + (size_t)(b * LQ_ + tl) * 384 + 256 + h * 16 + c4 + 2);
        v.w = __builtin_nontemporal_load(d12 + (size_t)(b * LQ_ + tl) * 384 + 256 + h * 16 + c4 + 3);
        *(float4*)&tls[trow][32 + c4] = v;
    }
    // stage refpts: 64 tokens x 2 float4 (threads 0..127)
    if (tid < 128) {
        int trow = tid >> 1;
        int c4   = (tid & 1) * 4;
        int tl   = min(t0 + trow, LQ_ - 1);
        float4 v;
        v.x = __builtin_nontemporal_load(refpts + (size_t)(b * LQ_ + tl) * 8 + c4 + 0);
        v.y = __builtin_nontemporal_load(refpts + (size_t)(b * LQ_ + tl) * 8 + c4 + 1);
        v.z = __builtin_nontemporal_load(refpts + (size_t)(b * LQ_ + tl) * 8 + c4 + 2);
        v.w = __builtin_nontemporal_load(refpts + (size_t)(b * LQ_ + tl) * 8 + c4 + 3);
        *(float4*)&tls[trow][48 + c4] = v;
    }
    __syncthreads();

    // softmax once per token (wave 0; 64 threads = 64 tokens)
    if (tid < 64) {
        float lg[16];
        float mx = -1e30f;
        #pragma unroll
        for (int i = 0; i < 16; ++i) { lg[i] = tls[tid][32 + i]; mx = fmaxf(mx, lg[i]); }
        float sum = 0.f;
        #pragma unroll
        for (int i = 0; i < 16; ++i) { lg[i] = __expf(lg[i] - mx); sum += lg[i]; }
        float inv = 1.f / sum;
        #pragma unroll
        for (int i = 0; i < 16; ++i) tls[tid][32 + i] = lg[i] * inv;
    }
    __syncthreads();

    const int wave = tid >> 6;
    const int lane = tid & 63;
    const int ti   = lane >> 2;            // token within wave [0,16)
    const int d8   = (lane & 3) * 8;
    const int row  = wave * 16 + ti;       // token within block [0,64)

    int tl = t0 + row;
    const bool active = (tl < LQ_);
    tl = min(tl, LQ_ - 1);
    const int tok = b * LQ_ + tl;

    const int HW[4]     = {128, 64, 32, 16};
    const int starts[4] = {0, 16384, 20480, 21504};

    const ushort_t* vplane = value + (size_t)combo * ((size_t)S_ * HD_) + d8;
    const float* trow = tls[row];

    float accv[8];
    #pragma unroll
    for (int i = 0; i < 8; ++i) accv[i] = 0.f;

    #pragma unroll
    for (int l = 0; l < 4; ++l) {
        const int Hl = HW[l], Wl = HW[l];
        float rx = trow[48 + l * 2 + 0];
        float ry = trow[48 + l * 2 + 1];
        const ushort_t* vbase = vplane + (size_t)starts[l] * HD_;
        #pragma unroll
        for (int p = 0; p < 4; ++p) {
            float ox = trow[l * 8 + p * 2 + 0];
            float oy = trow[l * 8 + p * 2 + 1];
            float aww = trow[32 + l * 4 + p];
            float xl = rx * (float)Wl + ox - 0.5f;
            float yl = ry * (float)Hl + oy - 0.5f;
            float x0f = floorf(xl), y0f = floorf(yl);
            int x0 = (int)x0f, y0 = (int)y0f;
            float wx1 = xl - x0f, wy1 = yl - y0f;
            float wx0 = 1.f - wx1, wy0 = 1.f - wy1;

            #pragma unroll
            for (int c = 0; c < 4; ++c) {
                int dx = c & 1, dy = c >> 1;
                int xi = x0 + dx, yi = y0 + dy;
                float w = (dx ? wx1 : wx0) * (dy ? wy1 : wy0);
                bool valid = (xi >= 0) & (xi < Wl) & (yi >= 0) & (yi < Hl);
                int xc = min(max(xi, 0), Wl - 1);
                int yc = min(max(yi, 0), Hl - 1);
                float wc = (valid ? w : 0.f) * aww;
                uint4 raw = *(const uint4*)(vbase + (size_t)(yc * Wl + xc) * HD_);
                accv[0] += __uint_as_float((raw.x & 0xFFFFu) << 16) * wc;
                accv[1] += __uint_as_float(raw.x & 0xFFFF0000u) * wc;
                accv[2] += __uint_as_float((raw.y & 0xFFFFu) << 16) * wc;
                accv[3] += __uint_as_float(raw.y & 0xFFFF0000u) * wc;
                accv[4] += __uint_as_float((raw.z & 0xFFFFu) << 16) * wc;
                accv[5] += __uint_as_float(raw.z & 0xFFFF0000u) * wc;
                accv[6] += __uint_as_float((raw.w & 0xFFFFu) << 16) * wc;
                accv[7] += __uint_as_float(raw.w & 0xFFFF0000u) * wc;
            }
        }
    }
    if (active) {
        uint4 po;
        po.x = pack_bf16(accv[0], accv[1]);
        po.y = pack_bf16(accv[2], accv[3]);
        po.z = pack_bf16(accv[4], accv[5]);
        po.w = pack_bf16(accv[6], accv[7]);
        *(uint4*)(out + (size_t)tok * C_ + h * HD_ + d8) = po;
    }
}

// ---------------- host launch ----------------
extern "C" void kernel_launch(void* const* d_in, const int* in_sizes, int n_in,
                              void* d_out, int out_size, void* d_ws, size_t ws_size,
                              hipStream_t stream) {
    const float* tgt_text = (const float*)d_in[0];
    const float* pos      = (const float*)d_in[1];
    const float* refpts   = (const float*)d_in[2];
    const float* src      = (const float*)d_in[3];
    const float* in_proj_w  = (const float*)d_in[6];
    const float* in_proj_b  = (const float*)d_in[7];
    const float* out_proj_w = (const float*)d_in[8];
    const float* out_proj_b = (const float*)d_in[9];
    const float* ln1_g = (const float*)d_in[10];
    const float* ln1_b = (const float*)d_in[11];
    const float* samp_off_w = (const float*)d_in[12];
    const float* samp_off_b = (const float*)d_in[13];
    const float* aw_w = (const float*)d_in[14];
    const float* aw_b = (const float*)d_in[15];
    const float* vp_w = (const float*)d_in[16];
    const float* vp_b = (const float*)d_in[17];
    const float* op_w = (const float*)d_in[18];
    const float* op_b = (const float*)d_in[19];
    const float* ln2_g = (const float*)d_in[20];
    const float* ln2_b = (const float*)d_in[21];
    const float* ffn1_w = (const float*)d_in[22];
    const float* ffn1_b = (const float*)d_in[23];
    const float* ffn2_w = (const float*)d_in[24];
    const float* ffn2_b = (const float*)d_in[25];
    const float* ln3_g = (const float*)d_in[26];
    const float* ln3_b = (const float*)d_in[27];

    const long long NC = (long long)NTOK_ * C_;    // 3,840,000 floats
    float* ws = (float*)d_ws;
    float* A    = ws;                               // [NTOK,C] fp32  tgt (post-LN1/LN2); also out-proj partial0
    float* Bq   = ws + NC;                          // [NTOK,C] fp32  query; also out-proj partial1
    float* Creg = ws + 2 * NC;                      // 15.36M floats: qkv+valt -> op partials -> ffn hidden
    float* D12  = Creg + (long long)NTOK_ * DFF_;   // [NTOK,384] fp32 offsets|aw
    float* E    = D12 + (long long)NTOK_ * 384;     // [NTOK,C]: bf16 attn/deform out; fp32 FFN2 partial0
    float* F    = E + NC;                           // [NTOK,C] fp32 FFN2 partial1
    ushort_t* wb = (ushort_t*)(F + NC);             // bf16 weight arena (~2 MB)

    ushort_t* qkv  = (ushort_t*)Creg;                       // [NTOK,768] bf16
    ushort_t* valt = (ushort_t*)Creg + (size_t)NTOK_ * 768; // [B][NH][S][HD] bf16

    // grid-x padded to %8==0 so same-x blocks share an XCD (pad blocks early-exit)
    const int MB64P  = 240;   // ceil(15000/64)=235 -> 240
    const int MB128P = 120;   // ceil(15000/128)=118 -> 120
    const int MBV64  = BS_ / 64;   // 680 (%8==0 already)

    // 0. convert all weights to bf16 (same rounding as per-tile pack -> bit-identical)
    convw_kernel<<<496, 256, 0, stream>>>(in_proj_w, out_proj_w, vp_w, samp_off_w,
                                          aw_w, op_w, ffn1_w, ffn2_w, wb);
    // 1. fused QKV projection -> qkv bf16 [NTOK,768]; n0<512 blocks add pos.
    gemm_w<1, 1, 64><<<dim3(MB64P, 6, 1), 256, 0, stream>>>(tgt_text, pos, wb + WOFF_IP,
        in_proj_b, nullptr, 512, qkv, 0, NTOK_, 768, 256, 256, 768, 0);
    // 3. value projection (src) -> valt bf16 transposed [B][NH][S][HD]
    gemm_w<0, 2, 64><<<dim3(MBV64, 2, 1), 256, 0, stream>>>(src, nullptr, wb + WOFF_VP,
        vp_b, nullptr, 0, valt, 0, BS_, 256, 256, 256, 0, 0);
    // 4. self-attention (bf16 -> bf16)
    attn_kernel<<<B_ * Q_ * NH_, 64, 0, stream>>>(qkv, (ushort_t*)E);
    // 5. out projection (A bf16), split-K x2 -> partials A, Bq (both free here)
    gemm_w<2, 0, 64><<<dim3(MB64P, 2, 2), 256, 0, stream>>>(E, nullptr, wb + WOFF_OUT,
        out_proj_b, nullptr, 0, ws, NC, NTOK_, 256, 256, 128, 256, 0);
    // 6. LN1 (residual = tgt + partial0 + partial1), and query = tgt + pos
    ln4_kernel<<<NTOK_ / 4, 256, 0, stream>>>(tgt_text, ws, 2, NC,
                                              ln1_g, ln1_b, A, pos, Bq);
    // 7. sampling offsets + aw logits (contiguous bf16 weights, dual bias) -> fp32 D12
    gemm_w<0, 0, 64><<<dim3(MB64P, 3, 1), 256, 0, stream>>>(Bq, nullptr, wb + WOFF_SO,
        samp_off_b, aw_b, 256, D12, 0, NTOK_, 384, 256, 256, 384, 0);
    // 8. deformable sampling (XCD-plane-local, LDS-staged params)
    deform_kernel<<<8 * 2 * DCHUNK_, 256, 0, stream>>>(valt, D12, refpts, (ushort_t*)E);
    // 9. output projection of cross-attn (A bf16), split-K x2 -> partials in Creg
    //    (qkv and valt are dead after steps 5 and 8)
    gemm_w<2, 0, 64><<<dim3(MB64P, 2, 2), 256, 0, stream>>>(E, nullptr, wb + WOFF_OP,
        op_b, nullptr, 0, Creg, NC, NTOK_, 256, 256, 128, 256, 0);
    // 10. LN2 (residual = A + partial0 + partial1), in place on A
    ln4_kernel<<<NTOK_ / 4, 256, 0, stream>>>(A, Creg, 2, NC,
                                              ln2_g, ln2_b, A, nullptr, nullptr);
    // 11. FFN1 + ReLU -> bf16 hidden [NTOK,1024]; 128-tile (overwrites op partials)
    gemm_w<0, 1, 128><<<dim3(MB128P, 8, 1), 256, 0, stream>>>(A, nullptr, wb + WOFF_F1,
        ffn1_b, nullptr, 0, Creg, 0, NTOK_, DFF_, 256, 256, DFF_, 1);
    // 12. FFN2 (A bf16), 128-tile + split-K x2: partial0=E, partial1=F (=E+NC)
    gemm_w<2, 0, 128><<<dim3(MB128P, 2, 2), 256, 0, stream>>>(Creg, nullptr, wb + WOFF_F2,
        ffn2_b, nullptr, 0, E, NC, NTOK_, 256, 1024, 512, 256, 0);
    // 13. LN3 (+ residual over 2 partials) -> d_out
    ln4_kernel<<<NTOK_ / 4, 256, 0, stream>>>(A, E, 2, NC,
                                              ln3_g, ln3_b, (float*)d_out, nullptr, nullptr);
}

// Round 7
// 384.177 us; speedup vs baseline: 1.0576x; 1.0576x over previous
//
#include <hip/hip_runtime.h>
#include <cstddef>

// Problem constants (static per reference)
#define B_ 2
#define Q_ 300
#define T_ 25
#define C_ 256
#define NH_ 8
#define NL_ 4
#define NP_ 4
#define HD_ 32
#define DFF_ 1024
#define LQ_ (Q_ * T_)           // 7500
#define NTOK_ (B_ * LQ_)        // 15000
#define S_ 21760                // sum of level sizes
#define BS_ (B_ * S_)           // 43520

typedef __bf16 bf16x8 __attribute__((ext_vector_type(8)));
typedef float floatx4 __attribute__((ext_vector_type(4)));
typedef unsigned short ushort_t;

// round-half-up bf16 pack: lo16 = bf16(x), hi16 = bf16(y). Folds to v_perm.
__device__ __forceinline__ unsigned pack_bf16(float x, float y) {
    unsigned ux = __float_as_uint(x) + 0x8000u;
    unsigned uy = __float_as_uint(y) + 0x8000u;
    return (ux >> 16) | (uy & 0xFFFF0000u);
}
__device__ __forceinline__ ushort_t f2bf_s(float x) {
    return (ushort_t)((__float_as_uint(x) + 0x8000u) >> 16);
}
__device__ __forceinline__ float bf2f(ushort_t u) {
    return __uint_as_float((unsigned)u << 16);
}

// bf16 weight arena element offsets (all static shapes)
#define WOFF_IP   0         // in_proj   768x256
#define WOFF_OUT  196608    // out_proj  256x256
#define WOFF_VP   262144    // value_proj 256x256
#define WOFF_SO   327680    // samp_off  256x256  (contiguous with aw -> 384x256)
#define WOFF_AW   393216    // aw        128x256
#define WOFF_OP   425984    // op        256x256
#define WOFF_F1   491520    // ffn1      1024x256
#define WOFF_F2   753664    // ffn2      256x1024
#define WTOTAL    1015808

// ---------------- one-shot fp32 -> bf16 weight conversion (8 elems/thread) ----------------
__global__ __launch_bounds__(256) void convw_kernel(
    const float* __restrict__ ipw, const float* __restrict__ outw,
    const float* __restrict__ vpw, const float* __restrict__ sampw,
    const float* __restrict__ aww, const float* __restrict__ opw,
    const float* __restrict__ f1w, const float* __restrict__ f2w,
    ushort_t* __restrict__ dst)
{
    long long g = ((long long)blockIdx.x * 256 + threadIdx.x) * 8;
    if (g >= WTOTAL) return;
    const float* src; long long off;
    if      (g < WOFF_OUT) { src = ipw;   off = WOFF_IP; }
    else if (g < WOFF_VP)  { src = outw;  off = WOFF_OUT; }
    else if (g < WOFF_SO)  { src = vpw;   off = WOFF_VP; }
    else if (g < WOFF_AW)  { src = sampw; off = WOFF_SO; }
    else if (g < WOFF_OP)  { src = aww;   off = WOFF_AW; }
    else if (g < WOFF_F1)  { src = opw;   off = WOFF_OP; }
    else if (g < WOFF_F2)  { src = f1w;   off = WOFF_F1; }
    else                   { src = f2w;   off = WOFF_F2; }
    const float4* s4 = (const float4*)(src + (g - off));
    float4 a = s4[0], b = s4[1];
    uint4 o;
    o.x = pack_bf16(a.x, a.y); o.y = pack_bf16(a.z, a.w);
    o.z = pack_bf16(b.x, b.y); o.w = pack_bf16(b.z, b.w);
    *(uint4*)(dst + g) = o;
}

#define GBN 128
#define GBK 64     // K-step: 2 MFMA-subtiles per barrier pair
#define LDA_S 72   // LDS row stride in bf16 (64 + 8 pad; 144B rows, 16B-aligned frags)

// ---------------- bf16-MFMA GEMM; W pre-converted bf16; 1-deep prefetch; split-K ----------
// AMODE: 0 = A fp32; 1 = A fp32 + A2 fp32 added ONLY for blocks with n0 < N1
//        (fused QKV); 2 = A bf16.
// OUTMODE: 0 = fp32 C (split-K capable; full-line stores already);
//          1 = bf16 C via LDS-restaged coalesced epilogue (full uint4 lines);
//          2 = bf16 C transposed value layout [B][NH][S][HD], same LDS restage.
// Grid-x padded to %8==0 by host (pad blocks exit on m0>=M): same-x blocks share
// an XCD -> A panel re-reads across y/z are L2 hits.
template<int AMODE, int OUTMODE, int GBMT>
__global__ __launch_bounds__(256) void gemm_w(
    const void* __restrict__ Av, const float* __restrict__ A2,
    const ushort_t* __restrict__ W,
    const float* __restrict__ bias, const float* __restrict__ bias2, int N1,
    void* __restrict__ Cv, long long partStride,
    int M, int N, int K, int kChunk, int ldc, int relu)
{
    constexpr int LA = GBMT / 16;   // A 4-elem chunks per thread
    constexpr int LB = 8;           // W 4-elem chunks per thread
    constexpr int WM = GBMT / 2;
    constexpr int NI = WM / 16;

    // union arena: staging tiles during K-loop; bf16 epilogue restage after
    __shared__ unsigned short SH[GBMT * LDA_S + GBN * LDA_S];
    unsigned short* Asl = SH;
    unsigned short* Bsl = SH + GBMT * LDA_S;

    const int m0 = blockIdx.x * GBMT;
    if (m0 >= M) return;                   // XCD-alignment pad block
    const int n0 = blockIdx.y * GBN;
    const int z  = blockIdx.z;
    const int kbeg = z * kChunk;
    const int kend = min(K, kbeg + kChunk);

    const int t  = threadIdx.x;
    const int wid  = t >> 6;
    const int lane = t & 63;
    const int wm = (wid >> 1) * WM;
    const int wn = (wid & 1) * 64;
    const int fm = lane & 15;
    const int fq = (lane >> 4) * 8;

    const bool addA2 = (AMODE == 1) && (n0 < N1);

    floatx4 acc[NI][4];
    #pragma unroll
    for (int i = 0; i < NI; ++i)
        #pragma unroll
        for (int j = 0; j < 4; ++j)
            acc[i][j] = (floatx4){0.f, 0.f, 0.f, 0.f};

    float4 pa[LA];
    uint2  pab[LA];
    uint2  pwb[LB];
    const float* Af = (const float*)Av;
    const ushort_t* Ab = (const ushort_t*)Av;

    auto load_tiles = [&](int k0) {
        #pragma unroll
        for (int i = 0; i < LA; ++i) {
            int idx = t + 256 * i;
            int row = idx >> 4;
            int c4  = (idx & 15) * 4;
            int gm = m0 + row;
            if constexpr (AMODE == 2) {
                uint2 v = {0u, 0u};
                if (gm < M) v = *(const uint2*)(Ab + (size_t)gm * K + k0 + c4);
                pab[i] = v;
            } else {
                float4 v = make_float4(0.f, 0.f, 0.f, 0.f);
                if (gm < M) {
                    v = *(const float4*)(Af + (size_t)gm * K + k0 + c4);
                    if constexpr (AMODE == 1) {
                        if (addA2) {
                            float4 v2 = *(const float4*)(A2 + (size_t)gm * K + k0 + c4);
                            v.x += v2.x; v.y += v2.y; v.z += v2.z; v.w += v2.w;
                        }
                    }
                }
                pa[i] = v;
            }
        }
        #pragma unroll
        for (int i = 0; i < LB; ++i) {
            int idx = t + 256 * i;
            int row = idx >> 4;
            int c4  = (idx & 15) * 4;
            pwb[i] = *(const uint2*)(W + (size_t)(n0 + row) * K + k0 + c4);
        }
    };

    load_tiles(kbeg);
    for (int k0 = kbeg; k0 < kend; k0 += GBK) {
        #pragma unroll
        for (int i = 0; i < LA; ++i) {
            int idx = t + 256 * i;
            int row = idx >> 4;
            int c4  = (idx & 15) * 4;
            if constexpr (AMODE == 2) {
                *(uint2*)&Asl[row * LDA_S + c4] = pab[i];
            } else {
                uint2 p;
                p.x = pack_bf16(pa[i].x, pa[i].y);
                p.y = pack_bf16(pa[i].z, pa[i].w);
                *(uint2*)&Asl[row * LDA_S + c4] = p;
            }
        }
        #pragma unroll
        for (int i = 0; i < LB; ++i) {
            int idx = t + 256 * i;
            int row = idx >> 4;
            int c4  = (idx & 15) * 4;
            *(uint2*)&Bsl[row * LDA_S + c4] = pwb[i];
        }
        __syncthreads();
        // issue next-tile loads here: they stay in flight across ds_read+MFMA
        if (k0 + GBK < kend) load_tiles(k0 + GBK);

        #pragma unroll
        for (int kk = 0; kk < 2; ++kk) {
            bf16x8 af[NI], bfr[4];
            #pragma unroll
            for (int i = 0; i < NI; ++i)
                af[i] = *(const bf16x8*)&Asl[(wm + i * 16 + fm) * LDA_S + kk * 32 + fq];
            #pragma unroll
            for (int j = 0; j < 4; ++j)
                bfr[j] = *(const bf16x8*)&Bsl[(wn + j * 16 + fm) * LDA_S + kk * 32 + fq];

            #pragma unroll
            for (int i = 0; i < NI; ++i)
                #pragma unroll
                for (int j = 0; j < 4; ++j)
                    acc[i][j] = __builtin_amdgcn_mfma_f32_16x16x32_bf16(af[i], bfr[j], acc[i][j], 0, 0, 0);
        }
        __syncthreads();
    }

    // epilogue: C/D layout col=lane&15, row=(lane>>4)*4+reg
    float* Cf = (float*)Cv + (long long)z * partStride;
    ushort_t* Cb = (ushort_t*)Cv;
    const int cr = (lane >> 4) * 4;
    const int cc = lane & 15;

    if constexpr (OUTMODE == 0) {
        // fp32: 16 lanes x 4B = 64B per row-quarter -> already full-line stores
        #pragma unroll
        for (int j = 0; j < 4; ++j) {
            int gn = n0 + wn + j * 16 + cc;
            float bia = 0.f;
            if (z == 0) bia = (bias2 && gn >= N1) ? bias2[gn - N1] : bias[gn];
            #pragma unroll
            for (int i = 0; i < NI; ++i)
                #pragma unroll
                for (int r = 0; r < 4; ++r) {
                    int gm = m0 + wm + i * 16 + cr + r;
                    if (gm < M) {
                        float v = acc[i][j][r] + bia;
                        if (relu) v = fmaxf(v, 0.f);
                        Cf[(size_t)gm * ldc + gn] = v;
                    }
                }
        }
    } else {
        // bf16: restage wave's WM x 64 sub-tile in LDS, then full-line uint4 stores.
        // Safe to reuse SH: final K-loop barrier ordered all ds_reads before here.
        unsigned short* epi = SH + wid * (WM * 64);
        #pragma unroll
        for (int j = 0; j < 4; ++j) {
            int gn = n0 + wn + j * 16 + cc;
            float bia = (bias2 && gn >= N1) ? bias2[gn - N1] : bias[gn];
            #pragma unroll
            for (int i = 0; i < NI; ++i)
                #pragma unroll
                for (int r = 0; r < 4; ++r) {
                    float v = acc[i][j][r] + bia;
                    if (relu) v = fmaxf(v, 0.f);
                    epi[(i * 16 + cr + r) * 64 + j * 16 + cc] = f2bf_s(v);
                }
        }
        // read back linear (lane l reads byte 16*l of the wave region: conflict-free)
        #pragma unroll
        for (int pass = 0; pass < WM / 8; ++pass) {
            int lr = pass * 8 + (lane >> 3);
            int gm = m0 + wm + lr;
            uint4 vv = *(const uint4*)&epi[lr * 64 + (lane & 7) * 8];
            if (gm < M) {
                if constexpr (OUTMODE == 1) {
                    *(uint4*)&Cb[(size_t)gm * ldc + n0 + wn + (lane & 7) * 8] = vv;
                } else {
                    int bb = gm >= S_;
                    int s  = gm - bb * S_;
                    int gh = n0 + wn + (lane & 7) * 8;   // 8 elems stay in one 32-col head
                    *(uint4*)&Cb[(((size_t)(bb * 8 + (gh >> 5))) * S_ + s) * 32 + (gh & 31)] = vv;
                }
            }
        }
    }
}

// ---------------- self-attention over T=25, one wave per (seq, head); bf16 in/out ----------------
__global__ __launch_bounds__(64) void attn_kernel(
    const ushort_t* __restrict__ qkv,   // [NTOK, 768] bf16: q|k|v per token
    ushort_t* __restrict__ o)           // [NTOK, 256] bf16
{
    int sh = blockIdx.x;
    int s = sh >> 3, h = sh & 7;
    __shared__ float qs[T_][HD_], ks[T_][HD_], vs[T_][HD_];
    int t = threadIdx.x;

    for (int idx = t; idx < T_ * HD_; idx += 64) {
        int i = idx >> 5, d = idx & 31;
        size_t base = ((size_t)(s * T_ + i)) * 768 + h * HD_ + d;
        qs[i][d] = bf2f(qkv[base]);
        ks[i][d] = bf2f(qkv[base + 256]);
        vs[i][d] = bf2f(qkv[base + 512]);
    }
    __syncthreads();

    if (t < T_) {
        float sc[T_];
        float mx = -1e30f;
        #pragma unroll
        for (int j = 0; j < T_; ++j) {
            float dot = 0.f;
            #pragma unroll
            for (int d = 0; d < HD_; ++d) dot += qs[t][d] * ks[j][d];
            sc[j] = dot * 0.17677669529663687f;
            mx = fmaxf(mx, sc[j]);
        }
        float sum = 0.f;
        #pragma unroll
        for (int j = 0; j < T_; ++j) { sc[j] = __expf(sc[j] - mx); sum += sc[j]; }
        float inv = 1.f / sum;
        float out[HD_];
        #pragma unroll
        for (int d = 0; d < HD_; ++d) out[d] = 0.f;
        for (int j = 0; j < T_; ++j) {
            float p = sc[j] * inv;
            #pragma unroll
            for (int d = 0; d < HD_; ++d) out[d] += p * vs[j][d];
        }
        size_t ob = ((size_t)(s * T_ + t)) * C_ + h * HD_;
        #pragma unroll
        for (int d = 0; d < HD_; ++d) o[ob + d] = f2bf_s(out[d]);
    }
}

// ---------------- wave-per-token residual + LayerNorm (float4, no LDS) ----------------
__global__ __launch_bounds__(256) void ln4_kernel(
    const float* x, const float* r,
    int nparts, long long rstride,
    const float* __restrict__ g, const float* __restrict__ b,
    float* out, const float* __restrict__ pos,
    float* qout)
{
    const int wave = threadIdx.x >> 6;
    const int lane = threadIdx.x & 63;
    const int tok = blockIdx.x * 4 + wave;
    const size_t base = (size_t)tok * C_ + lane * 4;

    float4 v = *(const float4*)(x + base);
    for (int p = 0; p < nparts; ++p) {
        float4 rv = *(const float4*)(r + base + (long long)p * rstride);
        v.x += rv.x; v.y += rv.y; v.z += rv.z; v.w += rv.w;
    }
    float s  = v.x + v.y + v.z + v.w;
    float ss = v.x * v.x + v.y * v.y + v.z * v.z + v.w * v.w;
    #pragma unroll
    for (int m = 32; m; m >>= 1) {
        s  += __shfl_xor(s, m);
        ss += __shfl_xor(ss, m);
    }
    float mean = s * (1.f / 256.f);
    float var  = ss * (1.f / 256.f) - mean * mean;
    float rstd = rsqrtf(var + 1e-5f);

    float4 gv = *(const float4*)(g + lane * 4);
    float4 bv = *(const float4*)(b + lane * 4);
    float4 y;
    y.x = (v.x - mean) * rstd * gv.x + bv.x;
    y.y = (v.y - mean) * rstd * gv.y + bv.y;
    y.z = (v.z - mean) * rstd * gv.z + bv.z;
    y.w = (v.w - mean) * rstd * gv.w + bv.w;
    *(float4*)(out + base) = y;
    if (qout) {
        float4 pv = *(const float4*)(pos + base);
        float4 q;
        q.x = y.x + pv.x; q.y = y.y + pv.y; q.z = y.z + pv.z; q.w = y.w + pv.w;
        *(float4*)(qout + base) = q;
    }
}

// ---------------- deformable sampling, XCD-plane-local + LDS params + batched gathers ----
// One block = one (b,h) plane x 64 tokens; wave = 16 tokens x 4 lanes (8 HD elems/lane).
// blockIdx.x % 8 -> XCD; per-XCD gather working set = 2 planes = 2.72 MB < 4 MB L2.
// Params staged in LDS; softmax computed once per token by wave 0.
// Gather loop: per level, ALL 16 (sample x corner) offsets+weights are computed
// first, then 16 uint4 loads issue back-to-back into a live register bank (64
// VGPR), then accumulate in the same (l,p,c) order as before -> bit-identical.
// launch_bounds(256,4): <=128 VGPR, 4 waves/SIMD -- 2x the loads-in-flight of the
// previous 52-VGPR version, which batched ~8 and stalled ~64% on L2 latency.
#define DCHUNK_ 118   // ceil(7500 / 64)
__global__ __launch_bounds__(256, 4) void deform_kernel(
    const ushort_t* __restrict__ value,   // [B][NH][S][HD] bf16 (transposed)
    const float* __restrict__ d12,        // [NTOK, 384] = offsets | aw logits
    const float* __restrict__ refpts,     // [B, LQ, NL, 2]
    ushort_t* __restrict__ out)           // [NTOK, 256] bf16, laid out (tok, h, d)
{
    const int bi    = blockIdx.x;          // [0, 8*2*DCHUNK_)
    const int xcd   = bi & 7;
    const int yy    = bi >> 3;
    const int combo = xcd + 8 * (yy & 1);  // == b*8 + h, in [0,16)
    const int chunk = yy >> 1;             // [0, DCHUNK_)
    const int h     = combo & 7;
    const int b     = combo >> 3;

    // per-token row: [0..31] offsets, [32..47] softmax weights, [48..55] refpts
    __shared__ float tls[64][60];

    const int tid = threadIdx.x;
    const int t0  = chunk * 64;

    // stage offsets: 64 tokens x 8 float4 (512 float4, 2/thread)
    #pragma unroll
    for (int i = 0; i < 2; ++i) {
        int idx  = tid + 256 * i;
        int trw  = idx >> 3;
        int c4   = (idx & 7) * 4;
        int tl   = min(t0 + trw, LQ_ - 1);
        float4 v;
        v.x = __builtin_nontemporal_load(d12 + (size_t)(b * LQ_ + tl) * 384 + h * 32 + c4 + 0);
        v.y = __builtin_nontemporal_load(d12 + (size_t)(b * LQ_ + tl) * 384 + h * 32 + c4 + 1);
        v.z = __builtin_nontemporal_load(d12 + (size_t)(b * LQ_ + tl) * 384 + h * 32 + c4 + 2);
        v.w = __builtin_nontemporal_load(d12 + (size_t)(b * LQ_ + tl) * 384 + h * 32 + c4 + 3);
        *(float4*)&tls[trw][c4] = v;
    }
    // stage aw logits: 64 tokens x 4 float4
    {
        int trw = tid >> 2;
        int c4  = (tid & 3) * 4;
        int tl  = min(t0 + trw, LQ_ - 1);
        float4 v;
        v.x = __builtin_nontemporal_load(d12 + (size_t)(b * LQ_ + tl) * 384 + 256 + h * 16 + c4 + 0);
        v.y = __builtin_nontemporal_load(d12 + (size_t)(b * LQ_ + tl) * 384 + 256 + h * 16 + c4 + 1);
        v.z = __builtin_nontemporal_load(d12 + (size_t)(b * LQ_ + tl) * 384 + 256 + h * 16 + c4 + 2);
        v.w = __builtin_nontemporal_load(d12 + (size_t)(b * LQ_ + tl) * 384 + 256 + h * 16 + c4 + 3);
        *(float4*)&tls[trw][32 + c4] = v;
    }
    // stage refpts: 64 tokens x 2 float4 (threads 0..127)
    if (tid < 128) {
        int trw = tid >> 1;
        int c4  = (tid & 1) * 4;
        int tl  = min(t0 + trw, LQ_ - 1);
        float4 v;
        v.x = __builtin_nontemporal_load(refpts + (size_t)(b * LQ_ + tl) * 8 + c4 + 0);
        v.y = __builtin_nontemporal_load(refpts + (size_t)(b * LQ_ + tl) * 8 + c4 + 1);
        v.z = __builtin_nontemporal_load(refpts + (size_t)(b * LQ_ + tl) * 8 + c4 + 2);
        v.w = __builtin_nontemporal_load(refpts + (size_t)(b * LQ_ + tl) * 8 + c4 + 3);
        *(float4*)&tls[trw][48 + c4] = v;
    }
    __syncthreads();

    // softmax once per token (wave 0; 64 threads = 64 tokens)
    if (tid < 64) {
        float lg[16];
        float mx = -1e30f;
        #pragma unroll
        for (int i = 0; i < 16; ++i) { lg[i] = tls[tid][32 + i]; mx = fmaxf(mx, lg[i]); }
        float sum = 0.f;
        #pragma unroll
        for (int i = 0; i < 16; ++i) { lg[i] = __expf(lg[i] - mx); sum += lg[i]; }
        float inv = 1.f / sum;
        #pragma unroll
        for (int i = 0; i < 16; ++i) tls[tid][32 + i] = lg[i] * inv;
    }
    __syncthreads();

    const int wave = tid >> 6;
    const int lane = tid & 63;
    const int ti   = lane >> 2;            // token within wave [0,16)
    const int d8   = (lane & 3) * 8;
    const int row  = wave * 16 + ti;       // token within block [0,64)

    int tl = t0 + row;
    const bool active = (tl < LQ_);
    tl = min(tl, LQ_ - 1);
    const int tok = b * LQ_ + tl;

    const int HW[4]     = {128, 64, 32, 16};
    const int starts[4] = {0, 16384, 20480, 21504};

    const ushort_t* vplane = value + (size_t)combo * ((size_t)S_ * HD_) + d8;
    const float* trow = tls[row];

    float accv[8];
    #pragma unroll
    for (int i = 0; i < 8; ++i) accv[i] = 0.f;

    #pragma unroll
    for (int l = 0; l < 4; ++l) {
        const int Hl = HW[l], Wl = HW[l];
        float rx = trow[48 + l * 2 + 0];
        float ry = trow[48 + l * 2 + 1];
        const ushort_t* vbase = vplane + (size_t)starts[l] * HD_;

        // phase 1: all 16 offsets + fused weights for this level
        int   voff[16];
        float wgt[16];
        #pragma unroll
        for (int p = 0; p < 4; ++p) {
            float ox = trow[l * 8 + p * 2 + 0];
            float oy = trow[l * 8 + p * 2 + 1];
            float aww = trow[32 + l * 4 + p];
            float xl = rx * (float)Wl + ox - 0.5f;
            float yl = ry * (float)Hl + oy - 0.5f;
            float x0f = floorf(xl), y0f = floorf(yl);
            int x0 = (int)x0f, y0 = (int)y0f;
            float wx1 = xl - x0f, wy1 = yl - y0f;
            float wx0 = 1.f - wx1, wy0 = 1.f - wy1;
            #pragma unroll
            for (int c = 0; c < 4; ++c) {
                int dx = c & 1, dy = c >> 1;
                int xi = x0 + dx, yi = y0 + dy;
                float w = (dx ? wx1 : wx0) * (dy ? wy1 : wy0);
                bool valid = (xi >= 0) & (xi < Wl) & (yi >= 0) & (yi < Hl);
                int xc = min(max(xi, 0), Wl - 1);
                int yc = min(max(yi, 0), Hl - 1);
                voff[p * 4 + c] = yc * Wl + xc;
                wgt[p * 4 + c]  = (valid ? w : 0.f) * aww;
            }
        }
        // phase 2: 16 loads in flight
        uint4 raw[16];
        #pragma unroll
        for (int i = 0; i < 16; ++i)
            raw[i] = *(const uint4*)(vbase + (size_t)voff[i] * HD_);
        // phase 3: accumulate in the same (p,c) order as the original -> identical FP
        #pragma unroll
        for (int i = 0; i < 16; ++i) {
            float wc = wgt[i];
            accv[0] += __uint_as_float((raw[i].x & 0xFFFFu) << 16) * wc;
            accv[1] += __uint_as_float(raw[i].x & 0xFFFF0000u) * wc;
            accv[2] += __uint_as_float((raw[i].y & 0xFFFFu) << 16) * wc;
            accv[3] += __uint_as_float(raw[i].y & 0xFFFF0000u) * wc;
            accv[4] += __uint_as_float((raw[i].z & 0xFFFFu) << 16) * wc;
            accv[5] += __uint_as_float(raw[i].z & 0xFFFF0000u) * wc;
            accv[6] += __uint_as_float((raw[i].w & 0xFFFFu) << 16) * wc;
            accv[7] += __uint_as_float(raw[i].w & 0xFFFF0000u) * wc;
        }
    }
    if (active) {
        uint4 po;
        po.x = pack_bf16(accv[0], accv[1]);
        po.y = pack_bf16(accv[2], accv[3]);
        po.z = pack_bf16(accv[4], accv[5]);
        po.w = pack_bf16(accv[6], accv[7]);
        *(uint4*)(out + (size_t)tok * C_ + h * HD_ + d8) = po;
    }
}

// ---------------- host launch ----------------
extern "C" void kernel_launch(void* const* d_in, const int* in_sizes, int n_in,
                              void* d_out, int out_size, void* d_ws, size_t ws_size,
                              hipStream_t stream) {
    const float* tgt_text = (const float*)d_in[0];
    const float* pos      = (const float*)d_in[1];
    const float* refpts   = (const float*)d_in[2];
    const float* src      = (const float*)d_in[3];
    const float* in_proj_w  = (const float*)d_in[6];
    const float* in_proj_b  = (const float*)d_in[7];
    const float* out_proj_w = (const float*)d_in[8];
    const float* out_proj_b = (const float*)d_in[9];
    const float* ln1_g = (const float*)d_in[10];
    const float* ln1_b = (const float*)d_in[11];
    const float* samp_off_w = (const float*)d_in[12];
    const float* samp_off_b = (const float*)d_in[13];
    const float* aw_w = (const float*)d_in[14];
    const float* aw_b = (const float*)d_in[15];
    const float* vp_w = (const float*)d_in[16];
    const float* vp_b = (const float*)d_in[17];
    const float* op_w = (const float*)d_in[18];
    const float* op_b = (const float*)d_in[19];
    const float* ln2_g = (const float*)d_in[20];
    const float* ln2_b = (const float*)d_in[21];
    const float* ffn1_w = (const float*)d_in[22];
    const float* ffn1_b = (const float*)d_in[23];
    const float* ffn2_w = (const float*)d_in[24];
    const float* ffn2_b = (const float*)d_in[25];
    const float* ln3_g = (const float*)d_in[26];
    const float* ln3_b = (const float*)d_in[27];

    const long long NC = (long long)NTOK_ * C_;    // 3,840,000 floats
    float* ws = (float*)d_ws;
    float* A    = ws;                               // [NTOK,C] fp32  tgt (post-LN1/LN2)
    float* Bq   = ws + NC;                          // [NTOK,C] fp32  query
    float* Creg = ws + 2 * NC;                      // 15.36M floats: qkv+valt -> ffn hidden
    float* D12  = Creg + (long long)NTOK_ * DFF_;   // [NTOK,384] fp32 offsets|aw
    float* E    = D12 + (long long)NTOK_ * 384;     // [NTOK,C]: bf16 attn/deform out; fp32 FFN2 partial0
    float* F    = E + NC;                           // [NTOK,C] fp32 proj results / FFN2 partial1
    ushort_t* wb = (ushort_t*)(F + NC);             // bf16 weight arena (~2 MB)

    ushort_t* qkv  = (ushort_t*)Creg;                       // [NTOK,768] bf16
    ushort_t* valt = (ushort_t*)Creg + (size_t)NTOK_ * 768; // [B][NH][S][HD] bf16

    // grid-x padded to %8==0 so same-x blocks share an XCD (pad blocks early-exit)
    const int MB64P  = 240;   // ceil(15000/64)=235 -> 240
    const int MB128P = 120;   // ceil(15000/128)=118 -> 120
    const int MBV64  = BS_ / 64;   // 680 (%8==0 already)

    // 0. convert all weights to bf16 (same rounding as per-tile pack -> bit-identical)
    convw_kernel<<<496, 256, 0, stream>>>(in_proj_w, out_proj_w, vp_w, samp_off_w,
                                          aw_w, op_w, ffn1_w, ffn2_w, wb);
    // 1. fused QKV projection -> qkv bf16 [NTOK,768]; n0<512 blocks add pos.
    gemm_w<1, 1, 64><<<dim3(MB64P, 6, 1), 256, 0, stream>>>(tgt_text, pos, wb + WOFF_IP,
        in_proj_b, nullptr, 512, qkv, 0, NTOK_, 768, 256, 256, 768, 0);
    // 3. value projection (src) -> valt bf16 transposed [B][NH][S][HD]
    gemm_w<0, 2, 64><<<dim3(MBV64, 2, 1), 256, 0, stream>>>(src, nullptr, wb + WOFF_VP,
        vp_b, nullptr, 0, valt, 0, BS_, 256, 256, 256, 0, 0);
    // 4. self-attention (bf16 -> bf16)
    attn_kernel<<<B_ * Q_ * NH_, 64, 0, stream>>>(qkv, (ushort_t*)E);
    // 5. out projection (A bf16) -> F fp32 (single-chunk K; split-K added net traffic)
    gemm_w<2, 0, 64><<<dim3(MB64P, 2, 1), 256, 0, stream>>>(E, nullptr, wb + WOFF_OUT,
        out_proj_b, nullptr, 0, F, 0, NTOK_, 256, 256, 256, 256, 0);
    // 6. LN1 (+ residual), and query = tgt + pos
    ln4_kernel<<<NTOK_ / 4, 256, 0, stream>>>(tgt_text, F, 1, 0,
                                              ln1_g, ln1_b, A, pos, Bq);
    // 7. sampling offsets + aw logits (contiguous bf16 weights, dual bias) -> fp32 D12
    gemm_w<0, 0, 64><<<dim3(MB64P, 3, 1), 256, 0, stream>>>(Bq, nullptr, wb + WOFF_SO,
        samp_off_b, aw_b, 256, D12, 0, NTOK_, 384, 256, 256, 384, 0);
    // 8. deformable sampling (XCD-plane-local, LDS params, 16-batched gathers)
    deform_kernel<<<8 * 2 * DCHUNK_, 256, 0, stream>>>(valt, D12, refpts, (ushort_t*)E);
    // 9. output projection of cross-attn (A bf16) -> F fp32
    gemm_w<2, 0, 64><<<dim3(MB64P, 2, 1), 256, 0, stream>>>(E, nullptr, wb + WOFF_OP,
        op_b, nullptr, 0, F, 0, NTOK_, 256, 256, 256, 256, 0);
    // 10. LN2 (+ residual), in place on A
    ln4_kernel<<<NTOK_ / 4, 256, 0, stream>>>(A, F, 1, 0,
                                              ln2_g, ln2_b, A, nullptr, nullptr);
    // 11. FFN1 + ReLU -> bf16 hidden [NTOK,1024]; 128-tile
    gemm_w<0, 1, 128><<<dim3(MB128P, 8, 1), 256, 0, stream>>>(A, nullptr, wb + WOFF_F1,
        ffn1_b, nullptr, 0, Creg, 0, NTOK_, DFF_, 256, 256, DFF_, 1);
    // 12. FFN2 (A bf16), 128-tile + split-K x2: partial0=E, partial1=F (=E+NC)
    gemm_w<2, 0, 128><<<dim3(MB128P, 2, 2), 256, 0, stream>>>(Creg, nullptr, wb + WOFF_F2,
        ffn2_b, nullptr, 0, E, NC, NTOK_, 256, 1024, 512, 256, 0);
    // 13. LN3 (+ residual over 2 partials) -> d_out
    ln4_kernel<<<NTOK_ / 4, 256, 0, stream>>>(A, E, 2, NC,
                                              ln3_g, ln3_b, (float*)d_out, nullptr, nullptr);
}

// Round 8
// 377.211 us; speedup vs baseline: 1.0771x; 1.0185x over previous
//
#include <hip/hip_runtime.h>
#include <cstddef>

// Problem constants (static per reference)
#define B_ 2
#define Q_ 300
#define T_ 25
#define C_ 256
#define NH_ 8
#define NL_ 4
#define NP_ 4
#define HD_ 32
#define DFF_ 1024
#define LQ_ (Q_ * T_)           // 7500
#define NTOK_ (B_ * LQ_)        // 15000
#define S_ 21760                // sum of level sizes
#define BS_ (B_ * S_)           // 43520

typedef __bf16 bf16x8 __attribute__((ext_vector_type(8)));
typedef float floatx4 __attribute__((ext_vector_type(4)));
typedef unsigned short ushort_t;

// round-half-up bf16 pack: lo16 = bf16(x), hi16 = bf16(y). Folds to v_perm.
__device__ __forceinline__ unsigned pack_bf16(float x, float y) {
    unsigned ux = __float_as_uint(x) + 0x8000u;
    unsigned uy = __float_as_uint(y) + 0x8000u;
    return (ux >> 16) | (uy & 0xFFFF0000u);
}
__device__ __forceinline__ ushort_t f2bf_s(float x) {
    return (ushort_t)((__float_as_uint(x) + 0x8000u) >> 16);
}
__device__ __forceinline__ float bf2f(ushort_t u) {
    return __uint_as_float((unsigned)u << 16);
}

// bf16 weight arena element offsets (all static shapes)
#define WOFF_IP   0         // in_proj   768x256
#define WOFF_OUT  196608    // out_proj  256x256
#define WOFF_VP   262144    // value_proj 256x256
#define WOFF_SO   327680    // samp_off  256x256  (contiguous with aw -> 384x256)
#define WOFF_AW   393216    // aw        128x256
#define WOFF_OP   425984    // op        256x256
#define WOFF_F1   491520    // ffn1      1024x256
#define WOFF_F2   753664    // ffn2      256x1024
#define WTOTAL    1015808

// ---------------- one-shot fp32 -> bf16 weight conversion (8 elems/thread) ----------------
__global__ __launch_bounds__(256) void convw_kernel(
    const float* __restrict__ ipw, const float* __restrict__ outw,
    const float* __restrict__ vpw, const float* __restrict__ sampw,
    const float* __restrict__ aww, const float* __restrict__ opw,
    const float* __restrict__ f1w, const float* __restrict__ f2w,
    ushort_t* __restrict__ dst)
{
    long long g = ((long long)blockIdx.x * 256 + threadIdx.x) * 8;
    if (g >= WTOTAL) return;
    const float* src; long long off;
    if      (g < WOFF_OUT) { src = ipw;   off = WOFF_IP; }
    else if (g < WOFF_VP)  { src = outw;  off = WOFF_OUT; }
    else if (g < WOFF_SO)  { src = vpw;   off = WOFF_VP; }
    else if (g < WOFF_AW)  { src = sampw; off = WOFF_SO; }
    else if (g < WOFF_OP)  { src = aww;   off = WOFF_AW; }
    else if (g < WOFF_F1)  { src = opw;   off = WOFF_OP; }
    else if (g < WOFF_F2)  { src = f1w;   off = WOFF_F1; }
    else                   { src = f2w;   off = WOFF_F2; }
    const float4* s4 = (const float4*)(src + (g - off));
    float4 a = s4[0], b = s4[1];
    uint4 o;
    o.x = pack_bf16(a.x, a.y); o.y = pack_bf16(a.z, a.w);
    o.z = pack_bf16(b.x, b.y); o.w = pack_bf16(b.z, b.w);
    *(uint4*)(dst + g) = o;
}

#define GBN 128
#define GBK 64     // K-step: 2 MFMA-subtiles per barrier pair
#define LDA_S 72   // LDS row stride in bf16 (64 + 8 pad; 144B rows, 16B-aligned frags)

// ---------------- bf16-MFMA GEMM; W pre-converted bf16; 1-deep prefetch ----------
// AMODE: 0 = A fp32; 1 = A fp32 + A2 fp32 added ONLY for blocks with n0 < N1
//        (fused QKV); 2 = A bf16.
// OUTMODE: 0 = fp32 C; 1 = bf16 C via LDS-restaged coalesced epilogue;
//          2 = bf16 C transposed value layout [B][NH][S][HD], same LDS restage.
// Grid-x padded to %8==0 by host (pad blocks exit on m0>=M): same-x blocks share
// an XCD -> A panel re-reads across y/z are L2 hits.
template<int AMODE, int OUTMODE, int GBMT>
__global__ __launch_bounds__(256) void gemm_w(
    const void* __restrict__ Av, const float* __restrict__ A2,
    const ushort_t* __restrict__ W,
    const float* __restrict__ bias, const float* __restrict__ bias2, int N1,
    void* __restrict__ Cv, long long partStride,
    int M, int N, int K, int kChunk, int ldc, int relu)
{
    constexpr int LA = GBMT / 16;   // A 4-elem chunks per thread
    constexpr int LB = 8;           // W 4-elem chunks per thread
    constexpr int WM = GBMT / 2;
    constexpr int NI = WM / 16;

    __shared__ unsigned short SH[GBMT * LDA_S + GBN * LDA_S];
    unsigned short* Asl = SH;
    unsigned short* Bsl = SH + GBMT * LDA_S;

    const int m0 = blockIdx.x * GBMT;
    if (m0 >= M) return;                   // XCD-alignment pad block
    const int n0 = blockIdx.y * GBN;
    const int z  = blockIdx.z;
    const int kbeg = z * kChunk;
    const int kend = min(K, kbeg + kChunk);

    const int t  = threadIdx.x;
    const int wid  = t >> 6;
    const int lane = t & 63;
    const int wm = (wid >> 1) * WM;
    const int wn = (wid & 1) * 64;
    const int fm = lane & 15;
    const int fq = (lane >> 4) * 8;

    const bool addA2 = (AMODE == 1) && (n0 < N1);

    floatx4 acc[NI][4];
    #pragma unroll
    for (int i = 0; i < NI; ++i)
        #pragma unroll
        for (int j = 0; j < 4; ++j)
            acc[i][j] = (floatx4){0.f, 0.f, 0.f, 0.f};

    float4 pa[LA];
    uint2  pab[LA];
    uint2  pwb[LB];
    const float* Af = (const float*)Av;
    const ushort_t* Ab = (const ushort_t*)Av;

    auto load_tiles = [&](int k0) {
        #pragma unroll
        for (int i = 0; i < LA; ++i) {
            int idx = t + 256 * i;
            int row = idx >> 4;
            int c4  = (idx & 15) * 4;
            int gm = m0 + row;
            if constexpr (AMODE == 2) {
                uint2 v = {0u, 0u};
                if (gm < M) v = *(const uint2*)(Ab + (size_t)gm * K + k0 + c4);
                pab[i] = v;
            } else {
                float4 v = make_float4(0.f, 0.f, 0.f, 0.f);
                if (gm < M) {
                    v = *(const float4*)(Af + (size_t)gm * K + k0 + c4);
                    if constexpr (AMODE == 1) {
                        if (addA2) {
                            float4 v2 = *(const float4*)(A2 + (size_t)gm * K + k0 + c4);
                            v.x += v2.x; v.y += v2.y; v.z += v2.z; v.w += v2.w;
                        }
                    }
                }
                pa[i] = v;
            }
        }
        #pragma unroll
        for (int i = 0; i < LB; ++i) {
            int idx = t + 256 * i;
            int row = idx >> 4;
            int c4  = (idx & 15) * 4;
            pwb[i] = *(const uint2*)(W + (size_t)(n0 + row) * K + k0 + c4);
        }
    };

    load_tiles(kbeg);
    for (int k0 = kbeg; k0 < kend; k0 += GBK) {
        #pragma unroll
        for (int i = 0; i < LA; ++i) {
            int idx = t + 256 * i;
            int row = idx >> 4;
            int c4  = (idx & 15) * 4;
            if constexpr (AMODE == 2) {
                *(uint2*)&Asl[row * LDA_S + c4] = pab[i];
            } else {
                uint2 p;
                p.x = pack_bf16(pa[i].x, pa[i].y);
                p.y = pack_bf16(pa[i].z, pa[i].w);
                *(uint2*)&Asl[row * LDA_S + c4] = p;
            }
        }
        #pragma unroll
        for (int i = 0; i < LB; ++i) {
            int idx = t + 256 * i;
            int row = idx >> 4;
            int c4  = (idx & 15) * 4;
            *(uint2*)&Bsl[row * LDA_S + c4] = pwb[i];
        }
        __syncthreads();
        if (k0 + GBK < kend) load_tiles(k0 + GBK);

        #pragma unroll
        for (int kk = 0; kk < 2; ++kk) {
            bf16x8 af[NI], bfr[4];
            #pragma unroll
            for (int i = 0; i < NI; ++i)
                af[i] = *(const bf16x8*)&Asl[(wm + i * 16 + fm) * LDA_S + kk * 32 + fq];
            #pragma unroll
            for (int j = 0; j < 4; ++j)
                bfr[j] = *(const bf16x8*)&Bsl[(wn + j * 16 + fm) * LDA_S + kk * 32 + fq];

            #pragma unroll
            for (int i = 0; i < NI; ++i)
                #pragma unroll
                for (int j = 0; j < 4; ++j)
                    acc[i][j] = __builtin_amdgcn_mfma_f32_16x16x32_bf16(af[i], bfr[j], acc[i][j], 0, 0, 0);
        }
        __syncthreads();
    }

    // epilogue: C/D layout col=lane&15, row=(lane>>4)*4+reg
    float* Cf = (float*)Cv + (long long)z * partStride;
    ushort_t* Cb = (ushort_t*)Cv;
    const int cr = (lane >> 4) * 4;
    const int cc = lane & 15;

    if constexpr (OUTMODE == 0) {
        #pragma unroll
        for (int j = 0; j < 4; ++j) {
            int gn = n0 + wn + j * 16 + cc;
            float bia = 0.f;
            if (z == 0) bia = (bias2 && gn >= N1) ? bias2[gn - N1] : bias[gn];
            #pragma unroll
            for (int i = 0; i < NI; ++i)
                #pragma unroll
                for (int r = 0; r < 4; ++r) {
                    int gm = m0 + wm + i * 16 + cr + r;
                    if (gm < M) {
                        float v = acc[i][j][r] + bia;
                        if (relu) v = fmaxf(v, 0.f);
                        Cf[(size_t)gm * ldc + gn] = v;
                    }
                }
        }
    } else {
        // bf16: restage wave's WM x 64 sub-tile in LDS, then full-line uint4 stores.
        unsigned short* epi = SH + wid * (WM * 64);
        #pragma unroll
        for (int j = 0; j < 4; ++j) {
            int gn = n0 + wn + j * 16 + cc;
            float bia = (bias2 && gn >= N1) ? bias2[gn - N1] : bias[gn];
            #pragma unroll
            for (int i = 0; i < NI; ++i)
                #pragma unroll
                for (int r = 0; r < 4; ++r) {
                    float v = acc[i][j][r] + bia;
                    if (relu) v = fmaxf(v, 0.f);
                    epi[(i * 16 + cr + r) * 64 + j * 16 + cc] = f2bf_s(v);
                }
        }
        #pragma unroll
        for (int pass = 0; pass < WM / 8; ++pass) {
            int lr = pass * 8 + (lane >> 3);
            int gm = m0 + wm + lr;
            uint4 vv = *(const uint4*)&epi[lr * 64 + (lane & 7) * 8];
            if (gm < M) {
                if constexpr (OUTMODE == 1) {
                    *(uint4*)&Cb[(size_t)gm * ldc + n0 + wn + (lane & 7) * 8] = vv;
                } else {
                    int bb = gm >= S_;
                    int s  = gm - bb * S_;
                    int gh = n0 + wn + (lane & 7) * 8;
                    *(uint4*)&Cb[(((size_t)(bb * 8 + (gh >> 5))) * S_ + s) * 32 + (gh & 31)] = vv;
                }
            }
        }
    }
}

// ---------------- fused GEMM (A bf16 x W[256,K]) + bias + residual + LayerNorm ----------
// Block = 64 rows x FULL N=256. 4 waves; wave w owns rows [w*16, w*16+16) x 256 cols
// (acc[16] f32x4). LN therefore never crosses a block. Epilogue: per 32-row half,
// the 2 owning waves dump acc+bias fp32 into LDS (stride 264 -> <=4-way bank
// aliasing), then ALL waves run the ln4 reduction verbatim (wave-per-row, 64
// lanes x float4, same shfl tree -> bit-identical LN math) with residual x fused,
// writing fp32 `outp` and optional `qout = y + pos`.
// x may alias outp (in-place LN2): each thread reads its own elems before writing.
template<int KSTEPS>   // K = KSTEPS*64
__global__ __launch_bounds__(256) void gemm_ln(
    const ushort_t* __restrict__ Ab,   // [M, K] bf16
    const ushort_t* __restrict__ W,    // [256, K] bf16
    const float* __restrict__ bias,    // [256]
    const float* x,                    // [M, 256] residual base (may alias outp)
    const float* __restrict__ g, const float* __restrict__ bv_,
    const float* __restrict__ pos,     // optional (qout)
    float* outp, float* qout, int M)
{
    constexpr int K = KSTEPS * 64;
    __shared__ unsigned short SH[(64 + 256) * LDA_S];   // 46080 B
    unsigned short* Asl = SH;
    unsigned short* Bsl = SH + 64 * LDA_S;

    const int m0 = blockIdx.x * 64;
    if (m0 >= M) return;

    const int t    = threadIdx.x;
    const int wid  = t >> 6;
    const int lane = t & 63;
    const int wm   = wid * 16;
    const int fm   = lane & 15;
    const int fq   = (lane >> 4) * 8;

    floatx4 acc[16];
    #pragma unroll
    for (int j = 0; j < 16; ++j) acc[j] = (floatx4){0.f, 0.f, 0.f, 0.f};

    uint2 pab[4];
    uint2 pwb[16];

    auto load_tiles = [&](int k0) {
        #pragma unroll
        for (int i = 0; i < 4; ++i) {
            int idx = t + 256 * i;
            int row = idx >> 4;
            int c4  = (idx & 15) * 4;
            int gm  = m0 + row;
            uint2 v = {0u, 0u};
            if (gm < M) v = *(const uint2*)(Ab + (size_t)gm * K + k0 + c4);
            pab[i] = v;
        }
        #pragma unroll
        for (int i = 0; i < 16; ++i) {
            int idx = t + 256 * i;
            int row = idx >> 4;
            int c4  = (idx & 15) * 4;
            pwb[i] = *(const uint2*)(W + (size_t)row * K + k0 + c4);
        }
    };

    load_tiles(0);
    #pragma unroll 1
    for (int ks = 0; ks < KSTEPS; ++ks) {
        #pragma unroll
        for (int i = 0; i < 4; ++i) {
            int idx = t + 256 * i;
            *(uint2*)&Asl[(idx >> 4) * LDA_S + (idx & 15) * 4] = pab[i];
        }
        #pragma unroll
        for (int i = 0; i < 16; ++i) {
            int idx = t + 256 * i;
            *(uint2*)&Bsl[(idx >> 4) * LDA_S + (idx & 15) * 4] = pwb[i];
        }
        __syncthreads();
        if (ks + 1 < KSTEPS) load_tiles((ks + 1) * 64);

        #pragma unroll
        for (int kk = 0; kk < 2; ++kk) {
            bf16x8 af = *(const bf16x8*)&Asl[(wm + fm) * LDA_S + kk * 32 + fq];
            #pragma unroll
            for (int j = 0; j < 16; ++j) {
                bf16x8 bfr = *(const bf16x8*)&Bsl[(j * 16 + fm) * LDA_S + kk * 32 + fq];
                acc[j] = __builtin_amdgcn_mfma_f32_16x16x32_bf16(af, bfr, acc[j], 0, 0, 0);
            }
        }
        __syncthreads();
    }

    // ---- fused epilogue: bias + residual + LN over 256 cols, 32 rows per phase ----
    const int cr = (lane >> 4) * 4;     // acc row sub-index
    const int cc = lane & 15;           // acc col sub-index
    float* ep = (float*)SH;             // [32][264] fp32 scratch (33792 B <= 46080)
    float4 gv = *(const float4*)(g   + lane * 4);
    float4 bb = *(const float4*)(bv_ + lane * 4);

    #pragma unroll
    for (int half = 0; half < 2; ++half) {
        if ((wid >> 1) == half) {
            int rbase = wm & 31;        // 0 or 16
            #pragma unroll
            for (int j = 0; j < 16; ++j) {
                float bia = bias[j * 16 + cc];
                #pragma unroll
                for (int r = 0; r < 4; ++r)
                    ep[(rbase + cr + r) * 264 + j * 16 + cc] = acc[j][r] + bia;
            }
        }
        __syncthreads();

        #pragma unroll
        for (int pass = 0; pass < 8; ++pass) {
            int rl   = pass * 4 + wid;          // 0..31
            int grow = m0 + half * 32 + rl;
            float4 v = *(const float4*)&ep[rl * 264 + lane * 4];
            if (grow < M) {
                float4 xv = *(const float4*)(x + (size_t)grow * 256 + lane * 4);
                v.x += xv.x; v.y += xv.y; v.z += xv.z; v.w += xv.w;
            }
            float s  = v.x + v.y + v.z + v.w;
            float ss = v.x * v.x + v.y * v.y + v.z * v.z + v.w * v.w;
            #pragma unroll
            for (int m = 32; m; m >>= 1) {
                s  += __shfl_xor(s, m);
                ss += __shfl_xor(ss, m);
            }
            float mean = s * (1.f / 256.f);
            float var  = ss * (1.f / 256.f) - mean * mean;
            float rstd = rsqrtf(var + 1e-5f);
            float4 y;
            y.x = (v.x - mean) * rstd * gv.x + bb.x;
            y.y = (v.y - mean) * rstd * gv.y + bb.y;
            y.z = (v.z - mean) * rstd * gv.z + bb.z;
            y.w = (v.w - mean) * rstd * gv.w + bb.w;
            if (grow < M) {
                *(float4*)(outp + (size_t)grow * 256 + lane * 4) = y;
                if (qout) {
                    float4 pv = *(const float4*)(pos + (size_t)grow * 256 + lane * 4);
                    float4 q;
                    q.x = y.x + pv.x; q.y = y.y + pv.y; q.z = y.z + pv.z; q.w = y.w + pv.w;
                    *(float4*)(qout + (size_t)grow * 256 + lane * 4) = q;
                }
            }
        }
        __syncthreads();
    }
}

// ---------------- self-attention over T=25, one wave per (seq, head); bf16 in/out ----------------
__global__ __launch_bounds__(64) void attn_kernel(
    const ushort_t* __restrict__ qkv,   // [NTOK, 768] bf16: q|k|v per token
    ushort_t* __restrict__ o)           // [NTOK, 256] bf16
{
    int sh = blockIdx.x;
    int s = sh >> 3, h = sh & 7;
    __shared__ float qs[T_][HD_], ks[T_][HD_], vs[T_][HD_];
    int t = threadIdx.x;

    for (int idx = t; idx < T_ * HD_; idx += 64) {
        int i = idx >> 5, d = idx & 31;
        size_t base = ((size_t)(s * T_ + i)) * 768 + h * HD_ + d;
        qs[i][d] = bf2f(qkv[base]);
        ks[i][d] = bf2f(qkv[base + 256]);
        vs[i][d] = bf2f(qkv[base + 512]);
    }
    __syncthreads();

    if (t < T_) {
        float sc[T_];
        float mx = -1e30f;
        #pragma unroll
        for (int j = 0; j < T_; ++j) {
            float dot = 0.f;
            #pragma unroll
            for (int d = 0; d < HD_; ++d) dot += qs[t][d] * ks[j][d];
            sc[j] = dot * 0.17677669529663687f;
            mx = fmaxf(mx, sc[j]);
        }
        float sum = 0.f;
        #pragma unroll
        for (int j = 0; j < T_; ++j) { sc[j] = __expf(sc[j] - mx); sum += sc[j]; }
        float inv = 1.f / sum;
        float out[HD_];
        #pragma unroll
        for (int d = 0; d < HD_; ++d) out[d] = 0.f;
        for (int j = 0; j < T_; ++j) {
            float p = sc[j] * inv;
            #pragma unroll
            for (int d = 0; d < HD_; ++d) out[d] += p * vs[j][d];
        }
        size_t ob = ((size_t)(s * T_ + t)) * C_ + h * HD_;
        #pragma unroll
        for (int d = 0; d < HD_; ++d) o[ob + d] = f2bf_s(out[d]);
    }
}

// ---------------- deformable sampling, XCD-plane-local + LDS params + batched gathers ----
#define DCHUNK_ 118   // ceil(7500 / 64)
__global__ __launch_bounds__(256, 4) void deform_kernel(
    const ushort_t* __restrict__ value,   // [B][NH][S][HD] bf16 (transposed)
    const float* __restrict__ d12,        // [NTOK, 384] = offsets | aw logits
    const float* __restrict__ refpts,     // [B, LQ, NL, 2]
    ushort_t* __restrict__ out)           // [NTOK, 256] bf16, laid out (tok, h, d)
{
    const int bi    = blockIdx.x;          // [0, 8*2*DCHUNK_)
    const int xcd   = bi & 7;
    const int yy    = bi >> 3;
    const int combo = xcd + 8 * (yy & 1);  // == b*8 + h, in [0,16)
    const int chunk = yy >> 1;             // [0, DCHUNK_)
    const int h     = combo & 7;
    const int b     = combo >> 3;

    __shared__ float tls[64][60];

    const int tid = threadIdx.x;
    const int t0  = chunk * 64;

    #pragma unroll
    for (int i = 0; i < 2; ++i) {
        int idx  = tid + 256 * i;
        int trw  = idx >> 3;
        int c4   = (idx & 7) * 4;
        int tl   = min(t0 + trw, LQ_ - 1);
        float4 v;
        v.x = __builtin_nontemporal_load(d12 + (size_t)(b * LQ_ + tl) * 384 + h * 32 + c4 + 0);
        v.y = __builtin_nontemporal_load(d12 + (size_t)(b * LQ_ + tl) * 384 + h * 32 + c4 + 1);
        v.z = __builtin_nontemporal_load(d12 + (size_t)(b * LQ_ + tl) * 384 + h * 32 + c4 + 2);
        v.w = __builtin_nontemporal_load(d12 + (size_t)(b * LQ_ + tl) * 384 + h * 32 + c4 + 3);
        *(float4*)&tls[trw][c4] = v;
    }
    {
        int trw = tid >> 2;
        int c4  = (tid & 3) * 4;
        int tl  = min(t0 + trw, LQ_ - 1);
        float4 v;
        v.x = __builtin_nontemporal_load(d12 + (size_t)(b * LQ_ + tl) * 384 + 256 + h * 16 + c4 + 0);
        v.y = __builtin_nontemporal_load(d12 + (size_t)(b * LQ_ + tl) * 384 + 256 + h * 16 + c4 + 1);
        v.z = __builtin_nontemporal_load(d12 + (size_t)(b * LQ_ + tl) * 384 + 256 + h * 16 + c4 + 2);
        v.w = __builtin_nontemporal_load(d12 + (size_t)(b * LQ_ + tl) * 384 + 256 + h * 16 + c4 + 3);
        *(float4*)&tls[trw][32 + c4] = v;
    }
    if (tid < 128) {
        int trw = tid >> 1;
        int c4  = (tid & 1) * 4;
        int tl  = min(t0 + trw, LQ_ - 1);
        float4 v;
        v.x = __builtin_nontemporal_load(refpts + (size_t)(b * LQ_ + tl) * 8 + c4 + 0);
        v.y = __builtin_nontemporal_load(refpts + (size_t)(b * LQ_ + tl) * 8 + c4 + 1);
        v.z = __builtin_nontemporal_load(refpts + (size_t)(b * LQ_ + tl) * 8 + c4 + 2);
        v.w = __builtin_nontemporal_load(refpts + (size_t)(b * LQ_ + tl) * 8 + c4 + 3);
        *(float4*)&tls[trw][48 + c4] = v;
    }
    __syncthreads();

    if (tid < 64) {
        float lg[16];
        float mx = -1e30f;
        #pragma unroll
        for (int i = 0; i < 16; ++i) { lg[i] = tls[tid][32 + i]; mx = fmaxf(mx, lg[i]); }
        float sum = 0.f;
        #pragma unroll
        for (int i = 0; i < 16; ++i) { lg[i] = __expf(lg[i] - mx); sum += lg[i]; }
        float inv = 1.f / sum;
        #pragma unroll
        for (int i = 0; i < 16; ++i) tls[tid][32 + i] = lg[i] * inv;
    }
    __syncthreads();

    const int wave = tid >> 6;
    const int lane = tid & 63;
    const int ti   = lane >> 2;
    const int d8   = (lane & 3) * 8;
    const int row  = wave * 16 + ti;

    int tl = t0 + row;
    const bool active = (tl < LQ_);
    tl = min(tl, LQ_ - 1);
    const int tok = b * LQ_ + tl;

    const int HW[4]     = {128, 64, 32, 16};
    const int starts[4] = {0, 16384, 20480, 21504};

    const ushort_t* vplane = value + (size_t)combo * ((size_t)S_ * HD_) + d8;
    const float* trow = tls[row];

    float accv[8];
    #pragma unroll
    for (int i = 0; i < 8; ++i) accv[i] = 0.f;

    #pragma unroll
    for (int l = 0; l < 4; ++l) {
        const int Hl = HW[l], Wl = HW[l];
        float rx = trow[48 + l * 2 + 0];
        float ry = trow[48 + l * 2 + 1];
        const ushort_t* vbase = vplane + (size_t)starts[l] * HD_;

        int   voff[16];
        float wgt[16];
        #pragma unroll
        for (int p = 0; p < 4; ++p) {
            float ox = trow[l * 8 + p * 2 + 0];
            float oy = trow[l * 8 + p * 2 + 1];
            float aww = trow[32 + l * 4 + p];
            float xl = rx * (float)Wl + ox - 0.5f;
            float yl = ry * (float)Hl + oy - 0.5f;
            float x0f = floorf(xl), y0f = floorf(yl);
            int x0 = (int)x0f, y0 = (int)y0f;
            float wx1 = xl - x0f, wy1 = yl - y0f;
            float wx0 = 1.f - wx1, wy0 = 1.f - wy1;
            #pragma unroll
            for (int c = 0; c < 4; ++c) {
                int dx = c & 1, dy = c >> 1;
                int xi = x0 + dx, yi = y0 + dy;
                float w = (dx ? wx1 : wx0) * (dy ? wy1 : wy0);
                bool valid = (xi >= 0) & (xi < Wl) & (yi >= 0) & (yi < Hl);
                int xc = min(max(xi, 0), Wl - 1);
                int yc = min(max(yi, 0), Hl - 1);
                voff[p * 4 + c] = yc * Wl + xc;
                wgt[p * 4 + c]  = (valid ? w : 0.f) * aww;
            }
        }
        uint4 raw[16];
        #pragma unroll
        for (int i = 0; i < 16; ++i)
            raw[i] = *(const uint4*)(vbase + (size_t)voff[i] * HD_);
        #pragma unroll
        for (int i = 0; i < 16; ++i) {
            float wc = wgt[i];
            accv[0] += __uint_as_float((raw[i].x & 0xFFFFu) << 16) * wc;
            accv[1] += __uint_as_float(raw[i].x & 0xFFFF0000u) * wc;
            accv[2] += __uint_as_float((raw[i].y & 0xFFFFu) << 16) * wc;
            accv[3] += __uint_as_float(raw[i].y & 0xFFFF0000u) * wc;
            accv[4] += __uint_as_float((raw[i].z & 0xFFFFu) << 16) * wc;
            accv[5] += __uint_as_float(raw[i].z & 0xFFFF0000u) * wc;
            accv[6] += __uint_as_float((raw[i].w & 0xFFFFu) << 16) * wc;
            accv[7] += __uint_as_float(raw[i].w & 0xFFFF0000u) * wc;
        }
    }
    if (active) {
        uint4 po;
        po.x = pack_bf16(accv[0], accv[1]);
        po.y = pack_bf16(accv[2], accv[3]);
        po.z = pack_bf16(accv[4], accv[5]);
        po.w = pack_bf16(accv[6], accv[7]);
        *(uint4*)(out + (size_t)tok * C_ + h * HD_ + d8) = po;
    }
}

// ---------------- host launch ----------------
extern "C" void kernel_launch(void* const* d_in, const int* in_sizes, int n_in,
                              void* d_out, int out_size, void* d_ws, size_t ws_size,
                              hipStream_t stream) {
    const float* tgt_text = (const float*)d_in[0];
    const float* pos      = (const float*)d_in[1];
    const float* refpts   = (const float*)d_in[2];
    const float* src      = (const float*)d_in[3];
    const float* in_proj_w  = (const float*)d_in[6];
    const float* in_proj_b  = (const float*)d_in[7];
    const float* out_proj_w = (const float*)d_in[8];
    const float* out_proj_b = (const float*)d_in[9];
    const float* ln1_g = (const float*)d_in[10];
    const float* ln1_b = (const float*)d_in[11];
    const float* samp_off_w = (const float*)d_in[12];
    const float* samp_off_b = (const float*)d_in[13];
    const float* aw_w = (const float*)d_in[14];
    const float* aw_b = (const float*)d_in[15];
    const float* vp_w = (const float*)d_in[16];
    const float* vp_b = (const float*)d_in[17];
    const float* op_w = (const float*)d_in[18];
    const float* op_b = (const float*)d_in[19];
    const float* ln2_g = (const float*)d_in[20];
    const float* ln2_b = (const float*)d_in[21];
    const float* ffn1_w = (const float*)d_in[22];
    const float* ffn1_b = (const float*)d_in[23];
    const float* ffn2_w = (const float*)d_in[24];
    const float* ffn2_b = (const float*)d_in[25];
    const float* ln3_g = (const float*)d_in[26];
    const float* ln3_b = (const float*)d_in[27];

    const long long NC = (long long)NTOK_ * C_;    // 3,840,000 floats
    float* ws = (float*)d_ws;
    float* A    = ws;                               // [NTOK,C] fp32  tgt (post-LN1/LN2)
    float* Bq   = ws + NC;                          // [NTOK,C] fp32  query
    float* Creg = ws + 2 * NC;                      // 15.36M floats: qkv+valt -> ffn hidden
    float* D12  = Creg + (long long)NTOK_ * DFF_;   // [NTOK,384] fp32 offsets|aw
    float* E    = D12 + (long long)NTOK_ * 384;     // [NTOK,C] bf16 attn/deform out
    float* F    = E + NC;                           // (unused; keeps wb offset stable)
    ushort_t* wb = (ushort_t*)(F + NC);             // bf16 weight arena (~2 MB)

    ushort_t* qkv  = (ushort_t*)Creg;                       // [NTOK,768] bf16
    ushort_t* valt = (ushort_t*)Creg + (size_t)NTOK_ * 768; // [B][NH][S][HD] bf16

    // grid-x padded to %8==0 so same-x blocks share an XCD (pad blocks early-exit)
    const int MB64P  = 240;   // ceil(15000/64)=235 -> 240
    const int MB128P = 120;   // ceil(15000/128)=118 -> 120
    const int MBV64  = BS_ / 64;   // 680 (%8==0 already)

    // 0. convert all weights to bf16 (same rounding as per-tile pack -> bit-identical)
    convw_kernel<<<496, 256, 0, stream>>>(in_proj_w, out_proj_w, vp_w, samp_off_w,
                                          aw_w, op_w, ffn1_w, ffn2_w, wb);
    // 1. fused QKV projection -> qkv bf16 [NTOK,768]; n0<512 blocks add pos.
    gemm_w<1, 1, 64><<<dim3(MB64P, 6, 1), 256, 0, stream>>>(tgt_text, pos, wb + WOFF_IP,
        in_proj_b, nullptr, 512, qkv, 0, NTOK_, 768, 256, 256, 768, 0);
    // 2. value projection (src) -> valt bf16 transposed [B][NH][S][HD]
    gemm_w<0, 2, 64><<<dim3(MBV64, 2, 1), 256, 0, stream>>>(src, nullptr, wb + WOFF_VP,
        vp_b, nullptr, 0, valt, 0, BS_, 256, 256, 256, 0, 0);
    // 3. self-attention (bf16 -> bf16)
    attn_kernel<<<B_ * Q_ * NH_, 64, 0, stream>>>(qkv, (ushort_t*)E);
    // 4. FUSED out-projection + residual(tgt) + LN1 -> A; query = A + pos -> Bq
    gemm_ln<4><<<MB64P, 256, 0, stream>>>((ushort_t*)E, wb + WOFF_OUT, out_proj_b,
        tgt_text, ln1_g, ln1_b, pos, A, Bq, NTOK_);
    // 5. sampling offsets + aw logits (contiguous bf16 weights, dual bias) -> fp32 D12
    gemm_w<0, 0, 64><<<dim3(MB64P, 3, 1), 256, 0, stream>>>(Bq, nullptr, wb + WOFF_SO,
        samp_off_b, aw_b, 256, D12, 0, NTOK_, 384, 256, 256, 384, 0);
    // 6. deformable sampling (XCD-plane-local, LDS params, 16-batched gathers)
    deform_kernel<<<8 * 2 * DCHUNK_, 256, 0, stream>>>(valt, D12, refpts, (ushort_t*)E);
    // 7. FUSED op-projection + residual(A) + LN2 -> A (in place; x==outp is safe)
    gemm_ln<4><<<MB64P, 256, 0, stream>>>((ushort_t*)E, wb + WOFF_OP, op_b,
        A, ln2_g, ln2_b, nullptr, A, nullptr, NTOK_);
    // 8. FFN1 + ReLU -> bf16 hidden [NTOK,1024]; 128-tile
    gemm_w<0, 1, 128><<<dim3(MB128P, 8, 1), 256, 0, stream>>>(A, nullptr, wb + WOFF_F1,
        ffn1_b, nullptr, 0, Creg, 0, NTOK_, DFF_, 256, 256, DFF_, 1);
    // 9. FUSED FFN2 + residual(A) + LN3 -> d_out (single K-chain, no split-K partials)
    gemm_ln<16><<<MB64P, 256, 0, stream>>>((ushort_t*)Creg, wb + WOFF_F2, ffn2_b,
        A, ln3_g, ln3_b, nullptr, (float*)d_out, nullptr, NTOK_);
}